// Round 3
// baseline (575.055 us; speedup 1.0000x reference)
//
#include <hip/hip_runtime.h>
#include <hip/hip_bf16.h>
#include <math.h>

#define D_MODEL 1024
#define SEQ 1024
#define BATCH 16
#define NROWS (BATCH * SEQ)   // 16384

typedef __bf16 bf16x8 __attribute__((ext_vector_type(8)));
typedef __bf16 bf16x4 __attribute__((ext_vector_type(4)));
typedef float f32x4 __attribute__((ext_vector_type(4)));
typedef __hip_bfloat16 bf16;

__device__ __forceinline__ float bf2f(bf16 v) { return __bfloat162float(v); }
__device__ __forceinline__ bf16 f2bf(float v) { return __float2bfloat16(v); }

__device__ __forceinline__ void gload_lds16(const bf16* g, bf16* l) {
    __builtin_amdgcn_global_load_lds(
        (const __attribute__((address_space(1))) void*)g,
        (__attribute__((address_space(3))) void*)l, 16, 0, 0);
}

// ---------------- all 4 weights fp32 -> bf16, one dispatch ----------------
__global__ void conv_w4_kernel(const float* __restrict__ s0, const float* __restrict__ s1,
                               const float* __restrict__ s2, const float* __restrict__ s3,
                               bf16* __restrict__ dst) {
    const float* srcs[4] = {s0, s1, s2, s3};
    const float* src = srcs[blockIdx.y];
    bf16* d = dst + (size_t)blockIdx.y * (D_MODEL * D_MODEL);
    int i = blockIdx.x * blockDim.x + threadIdx.x;
    int stride = gridDim.x * blockDim.x;
    for (; i < D_MODEL * D_MODEL; i += stride) d[i] = f2bf(src[i]);
}

// ---------------- fused LayerNorm + time-mix: one wave per row ----------------
__global__ __launch_bounds__(256) void lnmix_kernel(
    const float* __restrict__ x, const float* __restrict__ gamma, const float* __restrict__ beta,
    const float* __restrict__ tmk, const float* __restrict__ tmv, const float* __restrict__ tmr,
    bf16* __restrict__ xk, bf16* __restrict__ xv, bf16* __restrict__ xr)
{
    const int wave = threadIdx.x >> 6, lane = threadIdx.x & 63;
    const int row = blockIdx.x * 4 + wave;
    const int t = row & (SEQ - 1);
    const size_t base = (size_t)row * D_MODEL;

    float4 vc[4], vp[4];
    float sc = 0.f, sc2 = 0.f, sp = 0.f, sp2 = 0.f;
#pragma unroll
    for (int c = 0; c < 4; c++) {
        const int d = lane * 4 + c * 256;
        vc[c] = *reinterpret_cast<const float4*>(x + base + d);
        if (t == 0) { vp[c] = make_float4(0.f, 0.f, 0.f, 0.f); }
        else        { vp[c] = *reinterpret_cast<const float4*>(x + base - D_MODEL + d); }
        sc  += vc[c].x + vc[c].y + vc[c].z + vc[c].w;
        sc2 += vc[c].x * vc[c].x + vc[c].y * vc[c].y + vc[c].z * vc[c].z + vc[c].w * vc[c].w;
        sp  += vp[c].x + vp[c].y + vp[c].z + vp[c].w;
        sp2 += vp[c].x * vp[c].x + vp[c].y * vp[c].y + vp[c].z * vp[c].z + vp[c].w * vp[c].w;
    }
#pragma unroll
    for (int off = 1; off < 64; off <<= 1) {
        sc  += __shfl_xor(sc, off);
        sc2 += __shfl_xor(sc2, off);
        sp  += __shfl_xor(sp, off);
        sp2 += __shfl_xor(sp2, off);
    }
    const float muc = sc * (1.0f / D_MODEL);
    const float rc  = rsqrtf(sc2 * (1.0f / D_MODEL) - muc * muc + 1e-5f);
    const float mup = sp * (1.0f / D_MODEL);
    const float rp  = rsqrtf(sp2 * (1.0f / D_MODEL) - mup * mup + 1e-5f);

#pragma unroll
    for (int c = 0; c < 4; c++) {
        const int d = lane * 4 + c * 256;
        float4 g  = *reinterpret_cast<const float4*>(gamma + d);
        float4 b  = *reinterpret_cast<const float4*>(beta + d);
        float4 mk = *reinterpret_cast<const float4*>(tmk + d);
        float4 mv = *reinterpret_cast<const float4*>(tmv + d);
        float4 mr = *reinterpret_cast<const float4*>(tmr + d);
        float cn[4], pn[4];
        cn[0] = (vc[c].x - muc) * rc * g.x + b.x;
        cn[1] = (vc[c].y - muc) * rc * g.y + b.y;
        cn[2] = (vc[c].z - muc) * rc * g.z + b.z;
        cn[3] = (vc[c].w - muc) * rc * g.w + b.w;
        if (t == 0) { pn[0] = pn[1] = pn[2] = pn[3] = 0.f; }
        else {
            pn[0] = (vp[c].x - mup) * rp * g.x + b.x;
            pn[1] = (vp[c].y - mup) * rp * g.y + b.y;
            pn[2] = (vp[c].z - mup) * rp * g.z + b.z;
            pn[3] = (vp[c].w - mup) * rp * g.w + b.w;
        }
        const float mkv[4] = {mk.x, mk.y, mk.z, mk.w};
        const float mvv[4] = {mv.x, mv.y, mv.z, mv.w};
        const float mrv[4] = {mr.x, mr.y, mr.z, mr.w};
        bf16x4 ok, ov, orr;
#pragma unroll
        for (int e = 0; e < 4; e++) {
            ok[e]  = (__bf16)(mkv[e] * cn[e] + (1.0f - mkv[e]) * pn[e]);
            ov[e]  = (__bf16)(mvv[e] * cn[e] + (1.0f - mvv[e]) * pn[e]);
            orr[e] = (__bf16)(mrv[e] * cn[e] + (1.0f - mrv[e]) * pn[e]);
        }
        *reinterpret_cast<bf16x4*>(xk + base + d) = ok;
        *reinterpret_cast<bf16x4*>(xv + base + d) = ov;
        *reinterpret_cast<bf16x4*>(xr + base + d) = orr;
    }
}

// ---------------- dual GEMM K&V with fused ternary product epilogue ----------------
// kv[m,n] = ternary(Xk[m,:]@Wk[n,:]) * ternary(Xv[m,:]@Wv[n,:])
__global__ __launch_bounds__(256) void gemm_kv_kernel(
    const bf16* __restrict__ Xk, const bf16* __restrict__ Xv,
    const bf16* __restrict__ Wk, const bf16* __restrict__ Wv,
    bf16* __restrict__ KV)
{
    const int tid = threadIdx.x;
    const int lane = tid & 63, wave = tid >> 6;
    const int wm = wave >> 1, wn = wave & 1;
    const int mf = lane & 15, quad = lane >> 4;
    const int n0 = blockIdx.x * 128;
    const int m0 = blockIdx.y * 128;

    __shared__ bf16 Ak[128 * 32], Av[128 * 32];
    __shared__ bf16 Bk[128 * 32], Bv[128 * 32];

    f32x4 ck[4][4] = {};
    f32x4 cv[4][4] = {};

    const int r0  = tid >> 2;
    const int cc0 = (tid & 3) * 8;
    const int lo0 = wave * 512;          // LDS element offset, first 64-row half
    const int lo1 = 2048 + wave * 512;   // second half
    const size_t ga0 = (size_t)(m0 + r0) * D_MODEL + cc0;
    const size_t ga1 = (size_t)(m0 + r0 + 64) * D_MODEL + cc0;
    const size_t gb0 = (size_t)(n0 + r0) * D_MODEL + cc0;
    const size_t gb1 = (size_t)(n0 + r0 + 64) * D_MODEL + cc0;

    for (int k0 = 0; k0 < D_MODEL; k0 += 32) {
        __syncthreads();
        gload_lds16(Xk + ga0 + k0, Ak + lo0);
        gload_lds16(Xk + ga1 + k0, Ak + lo1);
        gload_lds16(Xv + ga0 + k0, Av + lo0);
        gload_lds16(Xv + ga1 + k0, Av + lo1);
        gload_lds16(Wk + gb0 + k0, Bk + lo0);
        gload_lds16(Wk + gb1 + k0, Bk + lo1);
        gload_lds16(Wv + gb0 + k0, Bv + lo0);
        gload_lds16(Wv + gb1 + k0, Bv + lo1);
        __syncthreads();
        bf16x8 afk[4], afv[4], bfk[4], bfv[4];
#pragma unroll
        for (int i = 0; i < 4; i++) {
            const int ao = (wm * 64 + i * 16 + mf) * 32 + quad * 8;
            afk[i] = *reinterpret_cast<const bf16x8*>(&Ak[ao]);
            afv[i] = *reinterpret_cast<const bf16x8*>(&Av[ao]);
        }
#pragma unroll
        for (int j = 0; j < 4; j++) {
            const int bo = (wn * 64 + j * 16 + mf) * 32 + quad * 8;
            bfk[j] = *reinterpret_cast<const bf16x8*>(&Bk[bo]);
            bfv[j] = *reinterpret_cast<const bf16x8*>(&Bv[bo]);
        }
#pragma unroll
        for (int i = 0; i < 4; i++)
#pragma unroll
            for (int j = 0; j < 4; j++) {
                ck[i][j] = __builtin_amdgcn_mfma_f32_16x16x32_bf16(afk[i], bfk[j], ck[i][j], 0, 0, 0);
                cv[i][j] = __builtin_amdgcn_mfma_f32_16x16x32_bf16(afv[i], bfv[j], cv[i][j], 0, 0, 0);
            }
    }

#pragma unroll
    for (int i = 0; i < 4; i++)
#pragma unroll
        for (int j = 0; j < 4; j++)
#pragma unroll
            for (int e = 0; e < 4; e++) {
                const int row = m0 + wm * 64 + i * 16 + quad * 4 + e;
                const int col = n0 + wn * 64 + j * 16 + mf;
                const float kk0 = ck[i][j][e];
                const float vv0 = cv[i][j][e];
                const float kk = (kk0 > 0.5f) ? 1.0f : ((kk0 < -0.5f) ? -1.0f : 0.0f);
                const float vv = (vv0 > 0.5f) ? 1.0f : ((vv0 < -0.5f) ? -1.0f : 0.0f);
                KV[(size_t)row * D_MODEL + col] = f2bf(kk * vv);
            }
}

// ---------------- dual GEMM R&Out with fused sigmoid/residual epilogue ----------------
// out[m,n] = x[m,n] + sigmoid(Xr[m,:]@Wr[n,:]) * (SA[m,:]@Wo[n,:])
__global__ __launch_bounds__(256) void gemm_ro_kernel(
    const bf16* __restrict__ Xr, const bf16* __restrict__ SA,
    const bf16* __restrict__ Wr, const bf16* __restrict__ Wo,
    const float* __restrict__ x, float* __restrict__ out)
{
    const int tid = threadIdx.x;
    const int lane = tid & 63, wave = tid >> 6;
    const int wm = wave >> 1, wn = wave & 1;
    const int mf = lane & 15, quad = lane >> 4;
    const int n0 = blockIdx.x * 128;
    const int m0 = blockIdx.y * 128;

    __shared__ bf16 Ar[128 * 32], Ao[128 * 32];
    __shared__ bf16 Br[128 * 32], Bo[128 * 32];

    f32x4 cr[4][4] = {};
    f32x4 co[4][4] = {};

    const int r0  = tid >> 2;
    const int cc0 = (tid & 3) * 8;
    const int lo0 = wave * 512;
    const int lo1 = 2048 + wave * 512;
    const size_t ga0 = (size_t)(m0 + r0) * D_MODEL + cc0;
    const size_t ga1 = (size_t)(m0 + r0 + 64) * D_MODEL + cc0;
    const size_t gb0 = (size_t)(n0 + r0) * D_MODEL + cc0;
    const size_t gb1 = (size_t)(n0 + r0 + 64) * D_MODEL + cc0;

    for (int k0 = 0; k0 < D_MODEL; k0 += 32) {
        __syncthreads();
        gload_lds16(Xr + ga0 + k0, Ar + lo0);
        gload_lds16(Xr + ga1 + k0, Ar + lo1);
        gload_lds16(SA + ga0 + k0, Ao + lo0);
        gload_lds16(SA + ga1 + k0, Ao + lo1);
        gload_lds16(Wr + gb0 + k0, Br + lo0);
        gload_lds16(Wr + gb1 + k0, Br + lo1);
        gload_lds16(Wo + gb0 + k0, Bo + lo0);
        gload_lds16(Wo + gb1 + k0, Bo + lo1);
        __syncthreads();
        bf16x8 afr[4], afo[4], bfr[4], bfo[4];
#pragma unroll
        for (int i = 0; i < 4; i++) {
            const int ao = (wm * 64 + i * 16 + mf) * 32 + quad * 8;
            afr[i] = *reinterpret_cast<const bf16x8*>(&Ar[ao]);
            afo[i] = *reinterpret_cast<const bf16x8*>(&Ao[ao]);
        }
#pragma unroll
        for (int j = 0; j < 4; j++) {
            const int bo = (wn * 64 + j * 16 + mf) * 32 + quad * 8;
            bfr[j] = *reinterpret_cast<const bf16x8*>(&Br[bo]);
            bfo[j] = *reinterpret_cast<const bf16x8*>(&Bo[bo]);
        }
#pragma unroll
        for (int i = 0; i < 4; i++)
#pragma unroll
            for (int j = 0; j < 4; j++) {
                cr[i][j] = __builtin_amdgcn_mfma_f32_16x16x32_bf16(afr[i], bfr[j], cr[i][j], 0, 0, 0);
                co[i][j] = __builtin_amdgcn_mfma_f32_16x16x32_bf16(afo[i], bfo[j], co[i][j], 0, 0, 0);
            }
    }

#pragma unroll
    for (int i = 0; i < 4; i++)
#pragma unroll
        for (int j = 0; j < 4; j++)
#pragma unroll
            for (int e = 0; e < 4; e++) {
                const int row = m0 + wm * 64 + i * 16 + quad * 4 + e;
                const int col = n0 + wn * 64 + j * 16 + mf;
                const size_t o = (size_t)row * D_MODEL + col;
                const float r = 1.0f / (1.0f + __expf(-cr[i][j][e]));
                out[o] = x[o] + r * co[i][j][e];
            }
}

// ---------------- recurrent scan: 4 T-chunks per channel, carry fix-up ----------------
__global__ __launch_bounds__(256) void scan_kernel(
    const bf16* __restrict__ KV, const float* __restrict__ dw, const float* __restrict__ S0,
    bf16* __restrict__ sall, float* __restrict__ sfinal)
{
    const int ch = threadIdx.x & 63;   // channel within group
    const int q  = threadIdx.x >> 6;   // T-chunk 0..3
    const int d  = blockIdx.x * 64 + ch;
    const int b  = blockIdx.y;
    const float dec = 1.0f / (1.0f + __expf(-dw[d]));
    float c256 = dec;
#pragma unroll
    for (int i = 0; i < 8; i++) c256 *= c256;   // dec^256

    const size_t base = ((size_t)b * SEQ + q * 256) * D_MODEL + d;

    // pass 1: local scan (zero-init), chunk-final only
    float S = 0.f;
    size_t idx = base;
    for (int t = 0; t < 256; t++, idx += D_MODEL)
        S = dec * S + bf2f(KV[idx]);

    __shared__ float Lf[4][64];
    __shared__ float P[4][64];
    Lf[q][ch] = S;
    __syncthreads();
    if (q == 0) {
        float p = S0[b * D_MODEL + d];      // true S_{-1}
        P[0][ch] = p;
        p = Lf[0][ch] + c256 * p; P[1][ch] = p;
        p = Lf[1][ch] + c256 * p; P[2][ch] = p;
        p = Lf[2][ch] + c256 * p; P[3][ch] = p;
        p = Lf[3][ch] + c256 * p;
        sfinal[b * D_MODEL + d] = p;
    }
    __syncthreads();

    // pass 2: scan with true incoming carry as init, store
    float Sv = P[q][ch];
    idx = base;
    for (int t = 0; t < 256; t++, idx += D_MODEL) {
        Sv = dec * Sv + bf2f(KV[idx]);
        sall[idx] = f2bf(Sv);
    }
}

extern "C" void kernel_launch(void* const* d_in, const int* in_sizes, int n_in,
                              void* d_out, int out_size, void* d_ws, size_t ws_size,
                              hipStream_t stream) {
    const float* x     = (const float*)d_in[0];
    const float* S0    = (const float*)d_in[1];
    const float* gamma = (const float*)d_in[2];
    const float* beta  = (const float*)d_in[3];
    const float* tmk   = (const float*)d_in[4];
    const float* tmv   = (const float*)d_in[5];
    const float* tmr   = (const float*)d_in[6];
    const float* dw    = (const float*)d_in[7];
    const float* Wk    = (const float*)d_in[8];
    const float* Wv    = (const float*)d_in[9];
    const float* Wr    = (const float*)d_in[10];
    const float* Wo    = (const float*)d_in[11];
    float* out = (float*)d_out;

    const int WN = D_MODEL * D_MODEL;             // 1048576
    const size_t MATN = (size_t)NROWS * D_MODEL;  // 16777216

    bf16* wsb  = (bf16*)d_ws;
    bf16* Wk_b = wsb;
    bf16* Wv_b = Wk_b + WN;
    bf16* Wr_b = Wv_b + WN;
    bf16* Wo_b = Wr_b + WN;
    bf16* XK = Wo_b + WN;
    bf16* XV = XK + MATN;
    bf16* XR = XV + MATN;
    bf16* KV = XR + MATN;
    bf16* SA = XK;              // XK (and XV) dead once gemm_kv completes; scan writes SA here

    conv_w4_kernel<<<dim3(256, 4), 256, 0, stream>>>(Wk, Wv, Wr, Wo, wsb);

    lnmix_kernel<<<NROWS / 4, 256, 0, stream>>>(x, gamma, beta, tmk, tmv, tmr, XK, XV, XR);

    dim3 ggrid(D_MODEL / 128, NROWS / 128);   // (8, 128)
    gemm_kv_kernel<<<ggrid, 256, 0, stream>>>(XK, XV, Wk_b, Wv_b, KV);

    scan_kernel<<<dim3(D_MODEL / 64, BATCH), 256, 0, stream>>>(KV, dw, S0, SA, out + MATN);

    gemm_ro_kernel<<<ggrid, 256, 0, stream>>>(XR, SA, Wr_b, Wo_b, x, out);
}

// Round 4
// 420.711 us; speedup vs baseline: 1.3669x; 1.3669x over previous
//
#include <hip/hip_runtime.h>
#include <hip/hip_bf16.h>
#include <math.h>

#define D_MODEL 1024
#define SEQ 1024
#define BATCH 16
#define NROWS (BATCH * SEQ)   // 16384

typedef __bf16 bf16x8 __attribute__((ext_vector_type(8)));
typedef __bf16 bf16x4 __attribute__((ext_vector_type(4)));
typedef float f32x4 __attribute__((ext_vector_type(4)));
typedef __hip_bfloat16 bf16;

__device__ __forceinline__ float bf2f(bf16 v) { return __bfloat162float(v); }
__device__ __forceinline__ bf16 f2bf(float v) { return __float2bfloat16(v); }

__device__ __forceinline__ void gload_lds16(const bf16* g, bf16* l) {
    __builtin_amdgcn_global_load_lds(
        (const __attribute__((address_space(1))) void*)g,
        (__attribute__((address_space(3))) void*)l, 16, 0, 0);
}

// XCD-aware swizzle: 1024 blocks -> each XCD gets a contiguous 16-block M-band
// (4 MB of A rows ~= one XCD's L2), swept across the 8 N-tiles.
__device__ __forceinline__ void tile_coords(int lin, int& m0, int& n0) {
    const int xcd = lin & 7;
    const int loc = lin >> 3;          // 0..127
    m0 = (xcd * 16 + (loc & 15)) * 128;
    n0 = (loc >> 4) * 128;             // 0..7
}

// ---------------- all 4 weights fp32 -> bf16, one dispatch ----------------
__global__ void conv_w4_kernel(const float* __restrict__ s0, const float* __restrict__ s1,
                               const float* __restrict__ s2, const float* __restrict__ s3,
                               bf16* __restrict__ dst) {
    const float* srcs[4] = {s0, s1, s2, s3};
    const float* src = srcs[blockIdx.y];
    bf16* d = dst + (size_t)blockIdx.y * (D_MODEL * D_MODEL);
    int i = blockIdx.x * blockDim.x + threadIdx.x;
    int stride = gridDim.x * blockDim.x;
    for (; i < D_MODEL * D_MODEL; i += stride) d[i] = f2bf(src[i]);
}

// ---------------- fused LayerNorm + time-mix: one wave per row ----------------
__global__ __launch_bounds__(256) void lnmix_kernel(
    const float* __restrict__ x, const float* __restrict__ gamma, const float* __restrict__ beta,
    const float* __restrict__ tmk, const float* __restrict__ tmv, const float* __restrict__ tmr,
    bf16* __restrict__ xk, bf16* __restrict__ xv, bf16* __restrict__ xr)
{
    const int wave = threadIdx.x >> 6, lane = threadIdx.x & 63;
    const int row = blockIdx.x * 4 + wave;
    const int t = row & (SEQ - 1);
    const size_t base = (size_t)row * D_MODEL;

    float4 vc[4], vp[4];
    float sc = 0.f, sc2 = 0.f, sp = 0.f, sp2 = 0.f;
#pragma unroll
    for (int c = 0; c < 4; c++) {
        const int d = lane * 4 + c * 256;
        vc[c] = *reinterpret_cast<const float4*>(x + base + d);
        if (t == 0) { vp[c] = make_float4(0.f, 0.f, 0.f, 0.f); }
        else        { vp[c] = *reinterpret_cast<const float4*>(x + base - D_MODEL + d); }
        sc  += vc[c].x + vc[c].y + vc[c].z + vc[c].w;
        sc2 += vc[c].x * vc[c].x + vc[c].y * vc[c].y + vc[c].z * vc[c].z + vc[c].w * vc[c].w;
        sp  += vp[c].x + vp[c].y + vp[c].z + vp[c].w;
        sp2 += vp[c].x * vp[c].x + vp[c].y * vp[c].y + vp[c].z * vp[c].z + vp[c].w * vp[c].w;
    }
#pragma unroll
    for (int off = 1; off < 64; off <<= 1) {
        sc  += __shfl_xor(sc, off);
        sc2 += __shfl_xor(sc2, off);
        sp  += __shfl_xor(sp, off);
        sp2 += __shfl_xor(sp2, off);
    }
    const float muc = sc * (1.0f / D_MODEL);
    const float rc  = rsqrtf(sc2 * (1.0f / D_MODEL) - muc * muc + 1e-5f);
    const float mup = sp * (1.0f / D_MODEL);
    const float rp  = rsqrtf(sp2 * (1.0f / D_MODEL) - mup * mup + 1e-5f);

#pragma unroll
    for (int c = 0; c < 4; c++) {
        const int d = lane * 4 + c * 256;
        float4 g  = *reinterpret_cast<const float4*>(gamma + d);
        float4 b  = *reinterpret_cast<const float4*>(beta + d);
        float4 mk = *reinterpret_cast<const float4*>(tmk + d);
        float4 mv = *reinterpret_cast<const float4*>(tmv + d);
        float4 mr = *reinterpret_cast<const float4*>(tmr + d);
        float cn[4], pn[4];
        cn[0] = (vc[c].x - muc) * rc * g.x + b.x;
        cn[1] = (vc[c].y - muc) * rc * g.y + b.y;
        cn[2] = (vc[c].z - muc) * rc * g.z + b.z;
        cn[3] = (vc[c].w - muc) * rc * g.w + b.w;
        if (t == 0) { pn[0] = pn[1] = pn[2] = pn[3] = 0.f; }
        else {
            pn[0] = (vp[c].x - mup) * rp * g.x + b.x;
            pn[1] = (vp[c].y - mup) * rp * g.y + b.y;
            pn[2] = (vp[c].z - mup) * rp * g.z + b.z;
            pn[3] = (vp[c].w - mup) * rp * g.w + b.w;
        }
        const float mkv[4] = {mk.x, mk.y, mk.z, mk.w};
        const float mvv[4] = {mv.x, mv.y, mv.z, mv.w};
        const float mrv[4] = {mr.x, mr.y, mr.z, mr.w};
        bf16x4 ok, ov, orr;
#pragma unroll
        for (int e = 0; e < 4; e++) {
            ok[e]  = (__bf16)(mkv[e] * cn[e] + (1.0f - mkv[e]) * pn[e]);
            ov[e]  = (__bf16)(mvv[e] * cn[e] + (1.0f - mvv[e]) * pn[e]);
            orr[e] = (__bf16)(mrv[e] * cn[e] + (1.0f - mrv[e]) * pn[e]);
        }
        *reinterpret_cast<bf16x4*>(xk + base + d) = ok;
        *reinterpret_cast<bf16x4*>(xv + base + d) = ov;
        *reinterpret_cast<bf16x4*>(xr + base + d) = orr;
    }
}

// ---------------- projection GEMM: C[m,n] = act(A[m,:] . W[n,:]) ----------------
// 128x128 tile, BK=64, single accumulator set. blockIdx.y picks (A,W,O) pair.
// MODE 0: ternary, 1: sigmoid.
template <int MODE>
__global__ __launch_bounds__(256) void gemm_proj_kernel(
    const bf16* __restrict__ A0, const bf16* __restrict__ A1,
    const bf16* __restrict__ W0, const bf16* __restrict__ W1,
    bf16* __restrict__ O0, bf16* __restrict__ O1)
{
    const bf16* A = blockIdx.y ? A1 : A0;
    const bf16* W = blockIdx.y ? W1 : W0;
    bf16* O       = blockIdx.y ? O1 : O0;

    const int tid = threadIdx.x;
    const int lane = tid & 63, wave = tid >> 6;
    const int wm = wave >> 1, wn = wave & 1;
    const int mf = lane & 15, quad = lane >> 4;
    int m0, n0;
    tile_coords(blockIdx.x, m0, n0);

    __shared__ bf16 As[128 * 64];
    __shared__ bf16 Bs[128 * 64];

    f32x4 acc[4][4] = {};

    const int trow = tid >> 3;          // 0..31: row within 32-row staging group
    const int tcol = (tid & 7) * 8;     // 8 bf16 = 16 B chunk

    for (int k0 = 0; k0 < D_MODEL; k0 += 64) {
        __syncthreads();
#pragma unroll
        for (int q = 0; q < 4; q++) {
            gload_lds16(A + (size_t)(m0 + q * 32 + trow) * D_MODEL + k0 + tcol,
                        As + q * 2048 + wave * 512);
            gload_lds16(W + (size_t)(n0 + q * 32 + trow) * D_MODEL + k0 + tcol,
                        Bs + q * 2048 + wave * 512);
        }
        __syncthreads();
#pragma unroll
        for (int s = 0; s < 2; s++) {
            bf16x8 af[4], bw[4];
#pragma unroll
            for (int i = 0; i < 4; i++)
                af[i] = *reinterpret_cast<const bf16x8*>(
                    &As[(wm * 64 + i * 16 + mf) * 64 + s * 32 + quad * 8]);
#pragma unroll
            for (int j = 0; j < 4; j++)
                bw[j] = *reinterpret_cast<const bf16x8*>(
                    &Bs[(wn * 64 + j * 16 + mf) * 64 + s * 32 + quad * 8]);
#pragma unroll
            for (int i = 0; i < 4; i++)
#pragma unroll
                for (int j = 0; j < 4; j++)
                    acc[i][j] = __builtin_amdgcn_mfma_f32_16x16x32_bf16(af[i], bw[j], acc[i][j], 0, 0, 0);
        }
    }

#pragma unroll
    for (int i = 0; i < 4; i++)
#pragma unroll
        for (int j = 0; j < 4; j++)
#pragma unroll
            for (int e = 0; e < 4; e++) {
                const int row = m0 + wm * 64 + i * 16 + quad * 4 + e;
                const int col = n0 + wn * 64 + j * 16 + mf;
                const float v = acc[i][j][e];
                float o;
                if (MODE == 0) o = (v > 0.5f) ? 1.0f : ((v < -0.5f) ? -1.0f : 0.0f);
                else           o = 1.0f / (1.0f + __expf(-v));
                O[(size_t)row * D_MODEL + col] = f2bf(o);
            }
}

// ---------------- output GEMM with residual epilogue ----------------
__global__ __launch_bounds__(256) void gemm_out_kernel(
    const bf16* __restrict__ SA, const bf16* __restrict__ Wo,
    const bf16* __restrict__ R, const float* __restrict__ x, float* __restrict__ out)
{
    const int tid = threadIdx.x;
    const int lane = tid & 63, wave = tid >> 6;
    const int wm = wave >> 1, wn = wave & 1;
    const int mf = lane & 15, quad = lane >> 4;
    int m0, n0;
    tile_coords(blockIdx.x, m0, n0);

    __shared__ bf16 As[128 * 64];
    __shared__ bf16 Bs[128 * 64];

    f32x4 acc[4][4] = {};

    const int trow = tid >> 3;
    const int tcol = (tid & 7) * 8;

    for (int k0 = 0; k0 < D_MODEL; k0 += 64) {
        __syncthreads();
#pragma unroll
        for (int q = 0; q < 4; q++) {
            gload_lds16(SA + (size_t)(m0 + q * 32 + trow) * D_MODEL + k0 + tcol,
                        As + q * 2048 + wave * 512);
            gload_lds16(Wo + (size_t)(n0 + q * 32 + trow) * D_MODEL + k0 + tcol,
                        Bs + q * 2048 + wave * 512);
        }
        __syncthreads();
#pragma unroll
        for (int s = 0; s < 2; s++) {
            bf16x8 af[4], bw[4];
#pragma unroll
            for (int i = 0; i < 4; i++)
                af[i] = *reinterpret_cast<const bf16x8*>(
                    &As[(wm * 64 + i * 16 + mf) * 64 + s * 32 + quad * 8]);
#pragma unroll
            for (int j = 0; j < 4; j++)
                bw[j] = *reinterpret_cast<const bf16x8*>(
                    &Bs[(wn * 64 + j * 16 + mf) * 64 + s * 32 + quad * 8]);
#pragma unroll
            for (int i = 0; i < 4; i++)
#pragma unroll
                for (int j = 0; j < 4; j++)
                    acc[i][j] = __builtin_amdgcn_mfma_f32_16x16x32_bf16(af[i], bw[j], acc[i][j], 0, 0, 0);
        }
    }

#pragma unroll
    for (int i = 0; i < 4; i++)
#pragma unroll
        for (int j = 0; j < 4; j++)
#pragma unroll
            for (int e = 0; e < 4; e++) {
                const int row = m0 + wm * 64 + i * 16 + quad * 4 + e;
                const int col = n0 + wn * 64 + j * 16 + mf;
                const size_t o = (size_t)row * D_MODEL + col;
                out[o] = x[o] + bf2f(R[o]) * acc[i][j][e];
            }
}

// ---------------- recurrent scan: 4 T-chunks per channel, carry fix-up ----------------
// kv = ternary(k)*ternary(v) values already in Kt/Vt (each {-1,0,1}); product here.
__global__ __launch_bounds__(256) void scan_kernel(
    const bf16* __restrict__ K, const bf16* __restrict__ V,
    const float* __restrict__ dw, const float* __restrict__ S0,
    bf16* __restrict__ sall, float* __restrict__ sfinal)
{
    const int ch = threadIdx.x & 63;   // channel within group
    const int q  = threadIdx.x >> 6;   // T-chunk 0..3
    const int d  = blockIdx.x * 64 + ch;
    const int b  = blockIdx.y;
    const float dec = 1.0f / (1.0f + __expf(-dw[d]));
    float c256 = dec;
#pragma unroll
    for (int i = 0; i < 8; i++) c256 *= c256;   // dec^256

    const size_t base = ((size_t)b * SEQ + q * 256) * D_MODEL + d;

    // pass 1: local scan (zero-init), chunk-final only
    float S = 0.f;
    size_t idx = base;
    for (int t = 0; t < 256; t++, idx += D_MODEL)
        S = dec * S + bf2f(K[idx]) * bf2f(V[idx]);

    __shared__ float Lf[4][64];
    __shared__ float P[4][64];
    Lf[q][ch] = S;
    __syncthreads();
    if (q == 0) {
        float p = S0[b * D_MODEL + d];      // true S_{-1}
        P[0][ch] = p;
        p = Lf[0][ch] + c256 * p; P[1][ch] = p;
        p = Lf[1][ch] + c256 * p; P[2][ch] = p;
        p = Lf[2][ch] + c256 * p; P[3][ch] = p;
        p = Lf[3][ch] + c256 * p;
        sfinal[b * D_MODEL + d] = p;
    }
    __syncthreads();

    // pass 2: scan with true incoming carry as init, store
    float Sv = P[q][ch];
    idx = base;
    for (int t = 0; t < 256; t++, idx += D_MODEL) {
        Sv = dec * Sv + bf2f(K[idx]) * bf2f(V[idx]);
        sall[idx] = f2bf(Sv);
    }
}

extern "C" void kernel_launch(void* const* d_in, const int* in_sizes, int n_in,
                              void* d_out, int out_size, void* d_ws, size_t ws_size,
                              hipStream_t stream) {
    const float* x     = (const float*)d_in[0];
    const float* S0    = (const float*)d_in[1];
    const float* gamma = (const float*)d_in[2];
    const float* beta  = (const float*)d_in[3];
    const float* tmk   = (const float*)d_in[4];
    const float* tmv   = (const float*)d_in[5];
    const float* tmr   = (const float*)d_in[6];
    const float* dw    = (const float*)d_in[7];
    const float* Wk    = (const float*)d_in[8];
    const float* Wv    = (const float*)d_in[9];
    const float* Wr    = (const float*)d_in[10];
    const float* Wo    = (const float*)d_in[11];
    float* out = (float*)d_out;

    const int WN = D_MODEL * D_MODEL;             // 1048576
    const size_t MATN = (size_t)NROWS * D_MODEL;  // 16777216

    // 8 MB weights + 5 x 32 MB matrix slots = 168 MB (same footprint as R1, known OK)
    bf16* wsb  = (bf16*)d_ws;
    bf16* Wk_b = wsb;
    bf16* Wv_b = Wk_b + WN;
    bf16* Wr_b = Wv_b + WN;
    bf16* Wo_b = Wr_b + WN;
    bf16* XK = Wo_b + WN;     // slot0: XK,  later RB (XK dead after gemm_kv)
    bf16* XV = XK + MATN;     // slot1: XV,  later SA (XV dead after gemm_kv)
    bf16* XR = XV + MATN;     // slot2: XR
    bf16* Kt = XR + MATN;     // slot3
    bf16* Vt = Kt + MATN;     // slot4
    bf16* RB = XK;
    bf16* SA = XV;

    conv_w4_kernel<<<dim3(256, 4), 256, 0, stream>>>(Wk, Wv, Wr, Wo, wsb);

    lnmix_kernel<<<NROWS / 4, 256, 0, stream>>>(x, gamma, beta, tmk, tmv, tmr, XK, XV, XR);

    // K and V projections in one dispatch (independent blocks, single acc set each)
    gemm_proj_kernel<0><<<dim3(1024, 2), 256, 0, stream>>>(XK, XV, Wk_b, Wv_b, Kt, Vt);

    // R projection (XK now dead -> RB reuses slot0)
    gemm_proj_kernel<1><<<dim3(1024, 1), 256, 0, stream>>>(XR, XR, Wr_b, Wr_b, RB, RB);

    // scan (XV now dead -> SA reuses slot1)
    scan_kernel<<<dim3(D_MODEL / 64, BATCH), 256, 0, stream>>>(Kt, Vt, dw, S0, SA, out + MATN);

    gemm_out_kernel<<<dim3(1024, 1), 256, 0, stream>>>(SA, Wo_b, RB, x, out);
}

// Round 5
// 401.193 us; speedup vs baseline: 1.4334x; 1.0487x over previous
//
#include <hip/hip_runtime.h>
#include <hip/hip_bf16.h>
#include <math.h>

#define D_MODEL 1024
#define SEQ 1024
#define BATCH 16
#define NROWS (BATCH * SEQ)   // 16384

typedef __bf16 bf16x8 __attribute__((ext_vector_type(8)));
typedef __bf16 bf16x4 __attribute__((ext_vector_type(4)));
typedef float f32x4 __attribute__((ext_vector_type(4)));
typedef __hip_bfloat16 bf16;

__device__ __forceinline__ float bf2f(bf16 v) { return __bfloat162float(v); }
__device__ __forceinline__ bf16 f2bf(float v) { return __float2bfloat16(v); }

__device__ __forceinline__ void gload_lds16(const bf16* g, bf16* l) {
    __builtin_amdgcn_global_load_lds(
        (const __attribute__((address_space(1))) void*)g,
        (__attribute__((address_space(3))) void*)l, 16, 0, 0);
}

// XCD-aware swizzle: 1024 blocks -> each XCD gets a contiguous 16-block M-band
// (4 MB of A rows ~= one XCD's L2), swept across the 8 N-tiles.
__device__ __forceinline__ void tile_coords(int lin, int& m0, int& n0) {
    const int xcd = lin & 7;
    const int loc = lin >> 3;          // 0..127
    m0 = (xcd * 16 + (loc & 15)) * 128;
    n0 = (loc >> 4) * 128;             // 0..7
}

// ---------------- all 4 weights fp32 -> bf16, one dispatch ----------------
__global__ void conv_w4_kernel(const float* __restrict__ s0, const float* __restrict__ s1,
                               const float* __restrict__ s2, const float* __restrict__ s3,
                               bf16* __restrict__ dst) {
    const float* srcs[4] = {s0, s1, s2, s3};
    const float* src = srcs[blockIdx.y];
    bf16* d = dst + (size_t)blockIdx.y * (D_MODEL * D_MODEL);
    int i = blockIdx.x * blockDim.x + threadIdx.x;
    int stride = gridDim.x * blockDim.x;
    for (; i < D_MODEL * D_MODEL; i += stride) d[i] = f2bf(src[i]);
}

// ---------------- fused LayerNorm + time-mix: one wave per row ----------------
__global__ __launch_bounds__(256) void lnmix_kernel(
    const float* __restrict__ x, const float* __restrict__ gamma, const float* __restrict__ beta,
    const float* __restrict__ tmk, const float* __restrict__ tmv, const float* __restrict__ tmr,
    bf16* __restrict__ xk, bf16* __restrict__ xv, bf16* __restrict__ xr)
{
    const int wave = threadIdx.x >> 6, lane = threadIdx.x & 63;
    const int row = blockIdx.x * 4 + wave;
    const int t = row & (SEQ - 1);
    const size_t base = (size_t)row * D_MODEL;

    float4 vc[4], vp[4];
    float sc = 0.f, sc2 = 0.f, sp = 0.f, sp2 = 0.f;
#pragma unroll
    for (int c = 0; c < 4; c++) {
        const int d = lane * 4 + c * 256;
        vc[c] = *reinterpret_cast<const float4*>(x + base + d);
        if (t == 0) { vp[c] = make_float4(0.f, 0.f, 0.f, 0.f); }
        else        { vp[c] = *reinterpret_cast<const float4*>(x + base - D_MODEL + d); }
        sc  += vc[c].x + vc[c].y + vc[c].z + vc[c].w;
        sc2 += vc[c].x * vc[c].x + vc[c].y * vc[c].y + vc[c].z * vc[c].z + vc[c].w * vc[c].w;
        sp  += vp[c].x + vp[c].y + vp[c].z + vp[c].w;
        sp2 += vp[c].x * vp[c].x + vp[c].y * vp[c].y + vp[c].z * vp[c].z + vp[c].w * vp[c].w;
    }
#pragma unroll
    for (int off = 1; off < 64; off <<= 1) {
        sc  += __shfl_xor(sc, off);
        sc2 += __shfl_xor(sc2, off);
        sp  += __shfl_xor(sp, off);
        sp2 += __shfl_xor(sp2, off);
    }
    const float muc = sc * (1.0f / D_MODEL);
    const float rc  = rsqrtf(sc2 * (1.0f / D_MODEL) - muc * muc + 1e-5f);
    const float mup = sp * (1.0f / D_MODEL);
    const float rp  = rsqrtf(sp2 * (1.0f / D_MODEL) - mup * mup + 1e-5f);

#pragma unroll
    for (int c = 0; c < 4; c++) {
        const int d = lane * 4 + c * 256;
        float4 g  = *reinterpret_cast<const float4*>(gamma + d);
        float4 b  = *reinterpret_cast<const float4*>(beta + d);
        float4 mk = *reinterpret_cast<const float4*>(tmk + d);
        float4 mv = *reinterpret_cast<const float4*>(tmv + d);
        float4 mr = *reinterpret_cast<const float4*>(tmr + d);
        float cn[4], pn[4];
        cn[0] = (vc[c].x - muc) * rc * g.x + b.x;
        cn[1] = (vc[c].y - muc) * rc * g.y + b.y;
        cn[2] = (vc[c].z - muc) * rc * g.z + b.z;
        cn[3] = (vc[c].w - muc) * rc * g.w + b.w;
        if (t == 0) { pn[0] = pn[1] = pn[2] = pn[3] = 0.f; }
        else {
            pn[0] = (vp[c].x - mup) * rp * g.x + b.x;
            pn[1] = (vp[c].y - mup) * rp * g.y + b.y;
            pn[2] = (vp[c].z - mup) * rp * g.z + b.z;
            pn[3] = (vp[c].w - mup) * rp * g.w + b.w;
        }
        const float mkv[4] = {mk.x, mk.y, mk.z, mk.w};
        const float mvv[4] = {mv.x, mv.y, mv.z, mv.w};
        const float mrv[4] = {mr.x, mr.y, mr.z, mr.w};
        bf16x4 ok, ov, orr;
#pragma unroll
        for (int e = 0; e < 4; e++) {
            ok[e]  = (__bf16)(mkv[e] * cn[e] + (1.0f - mkv[e]) * pn[e]);
            ov[e]  = (__bf16)(mvv[e] * cn[e] + (1.0f - mvv[e]) * pn[e]);
            orr[e] = (__bf16)(mrv[e] * cn[e] + (1.0f - mrv[e]) * pn[e]);
        }
        *reinterpret_cast<bf16x4*>(xk + base + d) = ok;
        *reinterpret_cast<bf16x4*>(xv + base + d) = ov;
        *reinterpret_cast<bf16x4*>(xr + base + d) = orr;
    }
}

// ---------------- projection GEMM: C[m,n] = act(A[m,:] . W[n,:]) ----------------
// 128x128 tile, BK=64, single accumulator set. blockIdx.y picks (A,W,O) pair.
// LDS layout XOR-swizzled on the 16B-chunk index to kill bank conflicts:
// LDS(row, c8) holds global chunk (c8 ^ (row&7)). MODE 0: ternary, 1: sigmoid.
template <int MODE>
__global__ __launch_bounds__(256) void gemm_proj_kernel(
    const bf16* __restrict__ A0, const bf16* __restrict__ A1,
    const bf16* __restrict__ W0, const bf16* __restrict__ W1,
    bf16* __restrict__ O0, bf16* __restrict__ O1)
{
    const bf16* A = blockIdx.y ? A1 : A0;
    const bf16* W = blockIdx.y ? W1 : W0;
    bf16* O       = blockIdx.y ? O1 : O0;

    const int tid = threadIdx.x;
    const int lane = tid & 63, wave = tid >> 6;
    const int wm = wave >> 1, wn = wave & 1;
    const int mf = lane & 15, quad = lane >> 4;
    int m0, n0;
    tile_coords(blockIdx.x, m0, n0);

    __shared__ bf16 As[128 * 64];
    __shared__ bf16 Bs[128 * 64];

    f32x4 acc[4][4] = {};

    const int trow = tid >> 3;                                  // 0..31 within staging group
    const int tcs  = (((tid & 7) ^ ((tid >> 3) & 7)) * 8);      // swizzled source chunk

    for (int k0 = 0; k0 < D_MODEL; k0 += 64) {
        __syncthreads();
#pragma unroll
        for (int q = 0; q < 4; q++) {
            gload_lds16(A + (size_t)(m0 + q * 32 + trow) * D_MODEL + k0 + tcs,
                        As + q * 2048 + wave * 512);
            gload_lds16(W + (size_t)(n0 + q * 32 + trow) * D_MODEL + k0 + tcs,
                        Bs + q * 2048 + wave * 512);
        }
        __syncthreads();
#pragma unroll
        for (int s = 0; s < 2; s++) {
            bf16x8 af[4], bw[4];
#pragma unroll
            for (int i = 0; i < 4; i++)
                af[i] = *reinterpret_cast<const bf16x8*>(
                    &As[(wm * 64 + i * 16 + mf) * 64 + (((s * 4 + quad) ^ (mf & 7)) * 8)]);
#pragma unroll
            for (int j = 0; j < 4; j++)
                bw[j] = *reinterpret_cast<const bf16x8*>(
                    &Bs[(wn * 64 + j * 16 + mf) * 64 + (((s * 4 + quad) ^ (mf & 7)) * 8)]);
#pragma unroll
            for (int i = 0; i < 4; i++)
#pragma unroll
                for (int j = 0; j < 4; j++)
                    acc[i][j] = __builtin_amdgcn_mfma_f32_16x16x32_bf16(af[i], bw[j], acc[i][j], 0, 0, 0);
        }
    }

#pragma unroll
    for (int i = 0; i < 4; i++)
#pragma unroll
        for (int j = 0; j < 4; j++)
#pragma unroll
            for (int e = 0; e < 4; e++) {
                const int row = m0 + wm * 64 + i * 16 + quad * 4 + e;
                const int col = n0 + wn * 64 + j * 16 + mf;
                const float v = acc[i][j][e];
                float o;
                if (MODE == 0) o = (v > 0.5f) ? 1.0f : ((v < -0.5f) ? -1.0f : 0.0f);
                else           o = 1.0f / (1.0f + __expf(-v));
                O[(size_t)row * D_MODEL + col] = f2bf(o);
            }
}

// ---------------- output GEMM with residual epilogue (same swizzled layout) ----------------
__global__ __launch_bounds__(256) void gemm_out_kernel(
    const bf16* __restrict__ SA, const bf16* __restrict__ Wo,
    const bf16* __restrict__ R, const float* __restrict__ x, float* __restrict__ out)
{
    const int tid = threadIdx.x;
    const int lane = tid & 63, wave = tid >> 6;
    const int wm = wave >> 1, wn = wave & 1;
    const int mf = lane & 15, quad = lane >> 4;
    int m0, n0;
    tile_coords(blockIdx.x, m0, n0);

    __shared__ bf16 As[128 * 64];
    __shared__ bf16 Bs[128 * 64];

    f32x4 acc[4][4] = {};

    const int trow = tid >> 3;
    const int tcs  = (((tid & 7) ^ ((tid >> 3) & 7)) * 8);

    for (int k0 = 0; k0 < D_MODEL; k0 += 64) {
        __syncthreads();
#pragma unroll
        for (int q = 0; q < 4; q++) {
            gload_lds16(SA + (size_t)(m0 + q * 32 + trow) * D_MODEL + k0 + tcs,
                        As + q * 2048 + wave * 512);
            gload_lds16(Wo + (size_t)(n0 + q * 32 + trow) * D_MODEL + k0 + tcs,
                        Bs + q * 2048 + wave * 512);
        }
        __syncthreads();
#pragma unroll
        for (int s = 0; s < 2; s++) {
            bf16x8 af[4], bw[4];
#pragma unroll
            for (int i = 0; i < 4; i++)
                af[i] = *reinterpret_cast<const bf16x8*>(
                    &As[(wm * 64 + i * 16 + mf) * 64 + (((s * 4 + quad) ^ (mf & 7)) * 8)]);
#pragma unroll
            for (int j = 0; j < 4; j++)
                bw[j] = *reinterpret_cast<const bf16x8*>(
                    &Bs[(wn * 64 + j * 16 + mf) * 64 + (((s * 4 + quad) ^ (mf & 7)) * 8)]);
#pragma unroll
            for (int i = 0; i < 4; i++)
#pragma unroll
                for (int j = 0; j < 4; j++)
                    acc[i][j] = __builtin_amdgcn_mfma_f32_16x16x32_bf16(af[i], bw[j], acc[i][j], 0, 0, 0);
        }
    }

#pragma unroll
    for (int i = 0; i < 4; i++)
#pragma unroll
        for (int j = 0; j < 4; j++)
#pragma unroll
            for (int e = 0; e < 4; e++) {
                const int row = m0 + wm * 64 + i * 16 + quad * 4 + e;
                const int col = n0 + wn * 64 + j * 16 + mf;
                const size_t o = (size_t)row * D_MODEL + col;
                out[o] = x[o] + bf2f(R[o]) * acc[i][j][e];
            }
}

// ---------------- recurrent scan: 4 T-chunks per channel, carry fix-up ----------------
__global__ __launch_bounds__(256) void scan_kernel(
    const bf16* __restrict__ K, const bf16* __restrict__ V,
    const float* __restrict__ dw, const float* __restrict__ S0,
    bf16* __restrict__ sall, float* __restrict__ sfinal)
{
    const int ch = threadIdx.x & 63;   // channel within group
    const int q  = threadIdx.x >> 6;   // T-chunk 0..3
    const int d  = blockIdx.x * 64 + ch;
    const int b  = blockIdx.y;
    const float dec = 1.0f / (1.0f + __expf(-dw[d]));
    float c256 = dec;
#pragma unroll
    for (int i = 0; i < 8; i++) c256 *= c256;   // dec^256

    const size_t base = ((size_t)b * SEQ + q * 256) * D_MODEL + d;

    // pass 1: local scan (zero-init), chunk-final only
    float S = 0.f;
    size_t idx = base;
    for (int t = 0; t < 256; t++, idx += D_MODEL)
        S = dec * S + bf2f(K[idx]) * bf2f(V[idx]);

    __shared__ float Lf[4][64];
    __shared__ float P[4][64];
    Lf[q][ch] = S;
    __syncthreads();
    if (q == 0) {
        float p = S0[b * D_MODEL + d];      // true S_{-1}
        P[0][ch] = p;
        p = Lf[0][ch] + c256 * p; P[1][ch] = p;
        p = Lf[1][ch] + c256 * p; P[2][ch] = p;
        p = Lf[2][ch] + c256 * p; P[3][ch] = p;
        p = Lf[3][ch] + c256 * p;
        sfinal[b * D_MODEL + d] = p;
    }
    __syncthreads();

    // pass 2: scan with true incoming carry as init, store
    float Sv = P[q][ch];
    idx = base;
    for (int t = 0; t < 256; t++, idx += D_MODEL) {
        Sv = dec * Sv + bf2f(K[idx]) * bf2f(V[idx]);
        sall[idx] = f2bf(Sv);
    }
}

extern "C" void kernel_launch(void* const* d_in, const int* in_sizes, int n_in,
                              void* d_out, int out_size, void* d_ws, size_t ws_size,
                              hipStream_t stream) {
    const float* x     = (const float*)d_in[0];
    const float* S0    = (const float*)d_in[1];
    const float* gamma = (const float*)d_in[2];
    const float* beta  = (const float*)d_in[3];
    const float* tmk   = (const float*)d_in[4];
    const float* tmv   = (const float*)d_in[5];
    const float* tmr   = (const float*)d_in[6];
    const float* dw    = (const float*)d_in[7];
    const float* Wk    = (const float*)d_in[8];
    const float* Wv    = (const float*)d_in[9];
    const float* Wr    = (const float*)d_in[10];
    const float* Wo    = (const float*)d_in[11];
    float* out = (float*)d_out;

    const int WN = D_MODEL * D_MODEL;             // 1048576
    const size_t MATN = (size_t)NROWS * D_MODEL;  // 16777216

    // 8 MB weights + 5 x 32 MB matrix slots = 168 MB
    bf16* wsb  = (bf16*)d_ws;
    bf16* Wk_b = wsb;
    bf16* Wv_b = Wk_b + WN;
    bf16* Wr_b = Wv_b + WN;
    bf16* Wo_b = Wr_b + WN;
    bf16* XK = Wo_b + WN;     // slot0: XK,  later RB (XK dead after gemm_kv)
    bf16* XV = XK + MATN;     // slot1: XV,  later SA (XV dead after gemm_kv)
    bf16* XR = XV + MATN;     // slot2: XR
    bf16* Kt = XR + MATN;     // slot3
    bf16* Vt = Kt + MATN;     // slot4
    bf16* RB = XK;
    bf16* SA = XV;

    conv_w4_kernel<<<dim3(256, 4), 256, 0, stream>>>(Wk, Wv, Wr, Wo, wsb);

    lnmix_kernel<<<NROWS / 4, 256, 0, stream>>>(x, gamma, beta, tmk, tmv, tmr, XK, XV, XR);

    // K and V projections in one dispatch (independent blocks, single acc set each)
    gemm_proj_kernel<0><<<dim3(1024, 2), 256, 0, stream>>>(XK, XV, Wk_b, Wv_b, Kt, Vt);

    // R projection (XK now dead -> RB reuses slot0)
    gemm_proj_kernel<1><<<dim3(1024, 1), 256, 0, stream>>>(XR, XR, Wr_b, Wr_b, RB, RB);

    // scan (XV now dead -> SA reuses slot1)
    scan_kernel<<<dim3(D_MODEL / 64, BATCH), 256, 0, stream>>>(Kt, Vt, dw, S0, SA, out + MATN);

    gemm_out_kernel<<<dim3(1024, 1), 256, 0, stream>>>(SA, Wo_b, RB, x, out);
}